// Round 5
// baseline (244.551 us; speedup 1.0000x reference)
//
#include <hip/hip_runtime.h>
#include <hip/hip_bf16.h>
#include <cstdint>
#include <cstddef>

// Problem constants (fixed shapes per reference)
#define NROWS 8192
#define DIM   1024
#define BMR 128           // block rows
#define BNC 128           // block cols
#define BK  64            // K depth per iteration; 16 iterations
#define NKT (DIM / BK)
#define NBLK 2080         // 64*65/2 triangle tiles = 8 XCDs x 260
#define EPS 1e-8f
// E pre-scaled by sqrt(10*log2(e)) so MFMA accumulates 10*log2(e)*<a,b>;
// epilogue is a bare exp2f.
#define PRESCALE 3.798288f

// LDS: 2 buffers x (A 128x64 + B 128x64) bf16 = 2 x 32 KB = 64 KB
#define ABUF_E 8192        // elems per A (or B) K-tile
#define BUF_E  16384       // elems per buffer (A ++ B)

typedef short  bf16x8  __attribute__((ext_vector_type(8)));
typedef float  floatx4 __attribute__((ext_vector_type(4)));

typedef __attribute__((address_space(1))) const void CGV;
typedef __attribute__((address_space(3))) void LV;

__device__ __forceinline__ void async_load16(const void* g, void* l) {
    __builtin_amdgcn_global_load_lds((CGV*)g, (LV*)l, 16, 0, 0);
}

__device__ __forceinline__ unsigned short f2bf_rne(float f) {
    union { float f; unsigned u; } c; c.f = f;
    unsigned u = c.u;
    unsigned r = (u + 0x7fffu + ((u >> 16) & 1u)) >> 16;
    return (unsigned short)r;
}

// ---------------------------------------------------------------------------
// Kernel A: fp32 -> bf16 (RNE) with PRESCALE folded in. First 64 blocks also
// zero the 16384-float accumulator region.
// ---------------------------------------------------------------------------
__global__ __launch_bounds__(256) void convert_kernel(
    const float* __restrict__ in, unsigned short* __restrict__ out,
    float* __restrict__ accum /* all_sum ++ pos_sum, 2*NROWS floats */)
{
    int i = (blockIdx.x * 256 + threadIdx.x) * 4;
    float4 v = *(const float4*)(in + i);
    ushort4 o;
    o.x = f2bf_rne(v.x * PRESCALE);
    o.y = f2bf_rne(v.y * PRESCALE);
    o.z = f2bf_rne(v.z * PRESCALE);
    o.w = f2bf_rne(v.w * PRESCALE);
    *(ushort4*)(out + i) = o;
    if (blockIdx.x < (2 * NROWS) / 256)
        accum[blockIdx.x * 256 + threadIdx.x] = 0.0f;
}

// ---------------------------------------------------------------------------
// Kernel B: symmetric-half fused GEMM, 128x128 tiles, STAGE-EARLY double
// buffer — the T3 "minimum 2-phase" structure (m97/m230-class, 682-912 TF):
//
//   STAGE(0 -> buf0); sync;
//   for kt: { STAGE(kt+1 -> buf[(kt+1)&1]);   // issued FIRST
//             ds_read + 32x2 MFMA from buf[kt&1];
//             __syncthreads(); }               // ONE barrier per K-step
//
// R5 post-mortem of R0-R4: every prior loop was sync->STAGE->sync->compute —
// staging issued immediately before the barrier that drains it (full L2
// latency + transfer serially exposed each K-step, zero stage||compute
// overlap). Here the mandatory vmcnt(0)-before-barrier is nearly free: the
// loads had the whole compute phase (~1.2k cy) to land. No inline asm, no
// sched_barrier — compiler-managed waits (m97 finding: near-optimal).
// Hazards with 1 barrier: iter-t STAGE writes buf[(t+1)&1] != read buf;
// that buffer was last read at iter t-1, fenced by iter t-1's barrier;
// STAGE(t)'s data drained by iter t's barrier before iter t+1 reads. Safe.
//
// 256 threads = 4 waves in 2x2 (m97's wave decomposition), acc[4][4]/wave;
// LDS 64 KB -> 2 blocks/CU (16 waves/CU) for cross-block overlap on top.
// Swizzle (R3/R9/R11-verified, BK=64/128B rows, 0 conflicts): LDS slot s of
// row r holds global chunk s^(r&7); linear LDS dest (m104) + pre-swizzled
// global source (m173); read slot = ((ksub*4+quad) ^ (colw&7)).
// UNIFORM symmetry (R11-verified, absmax 0): element (grow,gcol) counts iff
// grow > gcol; contributes to row grow AND col gcol — every unordered pair
// exactly once, diagonal tiles handled implicitly.
// ---------------------------------------------------------------------------
__global__ __launch_bounds__(256, 2) void gemm_fused_kernel(
    const unsigned short* __restrict__ E,   // bf16 bits (prescaled), [NROWS][DIM]
    const int*            __restrict__ labels,
    float*                __restrict__ all_sum,
    float*                __restrict__ pos_sum)
{
    __shared__ __align__(16) unsigned short S[2 * BUF_E];   // 64 KB

    const int tid  = threadIdx.x;
    const int lane = tid & 63;
    const int w    = tid >> 6;      // wave 0..3
    const int wm   = w >> 1;        // row half (64 rows)
    const int wn   = w & 1;         // col half (64 cols)
    const int colw = lane & 15;
    const int quad = lane >> 4;
    const int swz  = colw & 7;
    const int cs0  = ((0 | quad) ^ swz) << 3;   // ksub0 slot offset (elems)
    const int cs1  = ((4 | quad) ^ swz) << 3;   // ksub1

    // XCD-local linear tile id, then sqrt triangle decode (R0-verified).
    const int b = blockIdx.x;
    const int t = (b & 7) * 260 + (b >> 3);     // 2080 = 8 x 260
    int bi = (int)((sqrtf(8.0f * (float)t + 1.0f) - 1.0f) * 0.5f);
    while ((bi + 1) * (bi + 2) / 2 <= t) ++bi;
    while (bi * (bi + 1) / 2 > t) --bi;
    const int bj = t - bi * (bi + 1) / 2;

    const int rBase = bi * BMR;     // rows (A tile)
    const int cBase = bj * BNC;     // cols (B tile)

    // Staging: per K-step, A = 128x64 = 1024 chunks of 16B, B same; 256
    // threads x (4 A + 4 B). Wave w pass j covers rows w*8 + l8 + j*32,
    // chunk slot lane&7; LDS dest linear (elem = row*64 + slot*8 =
    // w*512 + lane*8 + j*2048); global source chunk = slot ^ (row&7),
    // row&7 = l8 (invariant under +32-row steps).
    const int l8  = lane >> 3;
    const int gch = (lane & 7) ^ l8;            // pre-swizzled global chunk
    const unsigned short* gA = E + (size_t)(rBase + w * 8 + l8) * DIM + gch * 8;
    const unsigned short* gB = E + (size_t)(cBase + w * 8 + l8) * DIM + gch * 8;
    const int ldsT = w * 512 + lane * 8;

#define STAGE(T, SB) do {                                                     \
        const size_t _gk = (size_t)(T) * BK;                                  \
        _Pragma("unroll")                                                     \
        for (int j = 0; j < 4; ++j) {                                         \
            async_load16(gA + (size_t)j * (32 * DIM) + _gk,                   \
                         &S[(SB) * BUF_E + j * 2048 + ldsT]);                 \
            async_load16(gB + (size_t)j * (32 * DIM) + _gk,                   \
                         &S[(SB) * BUF_E + ABUF_E + j * 2048 + ldsT]);        \
        }                                                                     \
    } while (0)

    floatx4 acc[4][4];
    #pragma unroll
    for (int i = 0; i < 4; ++i)
        #pragma unroll
        for (int j = 0; j < 4; ++j)
            acc[i][j] = (floatx4)0.0f;

    STAGE(0, 0);
    __syncthreads();    // compiler drains vmcnt before barrier — buf0 ready

    for (int kt = 0; kt < NKT; ++kt) {
        // Issue next tile's staging FIRST — overlaps the whole compute phase.
        if (kt < NKT - 1) STAGE(kt + 1, (kt + 1) & 1);

        const int bb = (kt & 1) * BUF_E;

        #pragma unroll
        for (int ksub = 0; ksub < 2; ++ksub) {
            const int cs = ksub ? cs1 : cs0;
            bf16x8 aF[4], bF[4];
            #pragma unroll
            for (int nt = 0; nt < 4; ++nt)
                bF[nt] = *(const bf16x8*)&S[bb + ABUF_E +
                              (wn * 64 + nt * 16 + colw) * BK + cs];
            #pragma unroll
            for (int mt = 0; mt < 4; ++mt)
                aF[mt] = *(const bf16x8*)&S[bb +
                              (wm * 64 + mt * 16 + colw) * BK + cs];
            #pragma unroll
            for (int mt = 0; mt < 4; ++mt)
                #pragma unroll
                for (int nt = 0; nt < 4; ++nt)
                    acc[mt][nt] = __builtin_amdgcn_mfma_f32_16x16x32_bf16(
                        aF[mt], bF[nt], acc[mt][nt], 0, 0, 0);
        }

        __syncthreads();    // one barrier per K-step: drains this iter's
                            // STAGE (issued a full compute phase ago) and
                            // fences buf reuse one iteration later
    }
#undef STAGE

    // Epilogue. C/D layout (16x16x32): col = lane&15, row = quad*4 + reg.
    // Uniform rule: element (grow, gcol) counts iff grow > gcol; contributes
    // to row grow AND col gcol (R11-verified).
    float labc[4];
    int   gcolv[4];
    #pragma unroll
    for (int nt = 0; nt < 4; ++nt) {
        gcolv[nt] = cBase + wn * 64 + nt * 16 + colw;
        labc[nt]  = (float)labels[gcolv[nt]];
    }

    float colAll[4] = {0.f, 0.f, 0.f, 0.f};
    float colPos[4] = {0.f, 0.f, 0.f, 0.f};

    #pragma unroll
    for (int mt = 0; mt < 4; ++mt) {
        const int growBase = rBase + wm * 64 + mt * 16 + quad * 4;
        #pragma unroll
        for (int r = 0; r < 4; ++r) {
            const int grow = growBase + r;
            const float labr = (float)labels[grow];
            float sAll = 0.f, sPos = 0.f;
            #pragma unroll
            for (int nt = 0; nt < 4; ++nt) {
                float ev = exp2f(acc[mt][nt][r]);   // PRESCALE folded into E
                ev = (grow > gcolv[nt]) ? ev : 0.0f; // strictly-lower only
                sAll += ev;
                sPos += ev * labc[nt];
                colAll[nt] += ev;
                colPos[nt] += ev * labr;
            }
            // row-reduce across the 16 lanes (same quad) sharing this row
            #pragma unroll
            for (int off = 1; off < 16; off <<= 1) {
                sAll += __shfl_xor(sAll, off);
                sPos += __shfl_xor(sPos, off);
            }
            if (colw == 0 && sAll != 0.f) {
                atomicAdd(&all_sum[grow], sAll);
                atomicAdd(&pos_sum[grow], sPos);
            }
        }
    }

    // col-reduce: sum across quads (lanes differing in bits 4,5)
    #pragma unroll
    for (int nt = 0; nt < 4; ++nt) {
        float aa = colAll[nt], p = colPos[nt];
        aa += __shfl_xor(aa, 16);  p += __shfl_xor(p, 16);
        aa += __shfl_xor(aa, 32);  p += __shfl_xor(p, 32);
        if (quad == 0 && aa != 0.f) {
            atomicAdd(&all_sum[gcolv[nt]], aa);
            atomicAdd(&pos_sum[gcolv[nt]], p);
        }
    }
}

// ---------------------------------------------------------------------------
// Kernel C: loss = mean over rows with lab==1 of -log(pos/(all+eps)); 0 if n_ref<2
// ---------------------------------------------------------------------------
__global__ __launch_bounds__(1024) void finalize_kernel(
    const float* __restrict__ all_sum,
    const float* __restrict__ pos_sum,
    const int*   __restrict__ labels,
    float*       __restrict__ out)
{
    __shared__ float sSum[1024];
    __shared__ float sCnt[1024];
    const int tid = threadIdx.x;
    float lsum = 0.f, lcnt = 0.f;
    for (int i = tid; i < NROWS; i += 1024) {
        if (labels[i] > 0) {
            float p = pos_sum[i];
            float a = all_sum[i] + EPS;
            lsum += -logf(p / a);
            lcnt += 1.0f;
        }
    }
    sSum[tid] = lsum;
    sCnt[tid] = lcnt;
    __syncthreads();
    for (int s = 512; s > 0; s >>= 1) {
        if (tid < s) { sSum[tid] += sSum[tid + s]; sCnt[tid] += sCnt[tid + s]; }
        __syncthreads();
    }
    if (tid == 0) {
        float n = sCnt[0];
        out[0] = (n < 2.0f) ? 0.0f : sSum[0] / fmaxf(n, 1.0f);
    }
}

// ---------------------------------------------------------------------------
extern "C" void kernel_launch(void* const* d_in, const int* in_sizes, int n_in,
                              void* d_out, int out_size, void* d_ws, size_t ws_size,
                              hipStream_t stream) {
    const float* emb    = (const float*)d_in[0];
    const int*   labels = (const int*)d_in[1];
    float*       out    = (float*)d_out;

    // workspace layout: [bf16 E: 16 MB][all_sum: 32 KB][pos_sum: 32 KB]
    unsigned short* Ebf = (unsigned short*)d_ws;
    const size_t embBytes = (size_t)NROWS * DIM * sizeof(unsigned short);
    float* all_sum = (float*)((char*)d_ws + embBytes);
    float* pos_sum = all_sum + NROWS;

    convert_kernel<<<(NROWS * DIM) / (4 * 256), 256, 0, stream>>>(emb, Ebf, all_sum);

    gemm_fused_kernel<<<NBLK, 256, 0, stream>>>(Ebf, labels, all_sum, pos_sum);

    finalize_kernel<<<1, 1024, 0, stream>>>(all_sum, pos_sum, labels, out);
}